// Round 2
// baseline (41.376 us; speedup 1.0000x reference)
//
#include <hip/hip_runtime.h>
#include <hip/hip_bf16.h>
#include <math.h>

#define IN_DIM   512
#define OUT_DIM  512
#define NK       192          // TOTAL_K
#define KF       384          // 2*TOTAL_K
#define XAVIER   0.04419417382415922f
#define BIAS_SCALE 0.02f

typedef __attribute__((ext_vector_type(8))) short bf16x8;
typedef __attribute__((ext_vector_type(4))) float f32x4;
typedef unsigned short u16;
typedef unsigned int   u32;
typedef unsigned long long u64;

__device__ inline u16 f2bf(float f) {
    __hip_bfloat16 h = __float2bfloat16(f);
    return *reinterpret_cast<u16*>(&h);
}
__device__ inline u32 pack2bf(float lo, float hi) {
    return (u32)f2bf(lo) | ((u32)f2bf(hi) << 16);
}
__device__ inline void gload_lds16(const void* g, void* l) {
    __builtin_amdgcn_global_load_lds(
        (const __attribute__((address_space(1))) void*)g,
        (__attribute__((address_space(3))) void*)l, 16, 0, 0);
}
// Native-rate sincos (revolutions). |arg| < ~50 rad here; err ~1e-6 << bf16 W quant.
__device__ inline void fsincos(float x, float& s, float& c) {
    float t = x * 0.15915494309189535f;   // 1/(2*pi)
    t -= floorf(t);
    s = __builtin_amdgcn_sinf(t);
    c = __builtin_amdgcn_cosf(t);
}

// ---------------------------------------------------------------------------
// Single fused kernel, 256 blocks x 512 threads, 1 block/CU (136KB LDS) so all
// blocks are co-resident -> manual device-scope grid barrier is safe.
//   Phase A: block b synthesizes Wt tile b (32x32) via angle-addition tables
//            + MFMA, and 2 bias entries (k-parallel, waves 4..7).
//   Barrier: atomic ticket, agent-scope acq/rel (cross-XCD L2 wb/inv).
//   Phase B: 32-row slice of out = x @ W + b with the counted-vmcnt
//            double-buffered 8-step pipeline (unchanged from prev round).
// LDS overlay: phase A tables live inside sB[1] (only touched post-barrier).
// ---------------------------------------------------------------------------
__global__ __launch_bounds__(512) void fourier_fused(
    const float* __restrict__ X,
    const float* __restrict__ omega, const float* __restrict__ phi,
    const float* __restrict__ alpha, const float* __restrict__ alpha_bias,
    const int* __restrict__ layer_idx, const int* __restrict__ num_layers,
    u16* __restrict__ Wt, float* __restrict__ bias,
    u32* __restrict__ ctr, float* __restrict__ out, int M)
{
    __shared__ __align__(16) char smem[136 * 1024];
    // phase B regions
    char* const sA  = smem;                 // 2 x 4KB  [0, 8K)
    char* const sB  = smem + 8 * 1024;      // 2 x 64KB [8K, 136K)
    // phase A overlay (inside sB[1] = [72K,136K))
    char*  const sU  = smem + 72 * 1024;    // 24KB
    char*  const sV  = smem + 96 * 1024;    // 24KB
    float* const bsc = (float*)(smem + 120 * 1024);

    const int b   = blockIdx.x;
    const int tid = threadIdx.x;
    const float l = ((float)layer_idx[0] + 1.0f) / ((float)num_layers[0] + 1.0f);

    // ======================= Phase A: synthesis ==========================
    {
        const int bi = b & 15, bj = b >> 4;
        const int i0 = bi * 32, j0 = bj * 32;

        #pragma unroll 4
        for (int q = 0; q < 12; ++q) {
            const int e  = q * 512 + tid;     // 0..6143
            const int rl = e / NK;
            const int k  = e - rl * NK;
            const int swz  = (rl & 7) << 4;
            const int base = rl * (KF * 2);
            const float om0 = omega[3*k], om1 = omega[3*k+1], om2 = omega[3*k+2];
            const float ph  = phi[k];
            {
                const float ii = (i0 + rl + 1.0f) * (1.0f / (IN_DIM + 1.0f));
                float s, c; fsincos(fmaf(ii, om0, fmaf(l, om2, ph)), s, c);
                *(u16*)(sU + base + (((2*k)      ) ^ swz)) = f2bf(s);
                *(u16*)(sU + base + (((2*k) + 384) ^ swz)) = f2bf(c);
            }
            {
                const float jj = (j0 + rl + 1.0f) * (1.0f / (OUT_DIM + 1.0f));
                float sv, cv; fsincos(jj * om1, sv, cv);
                const float as = alpha[k], ac = alpha[NK + k];
                *(u16*)(sV + base + (((2*k)      ) ^ swz)) = f2bf((as*cv - ac*sv) * XAVIER);
                *(u16*)(sV + base + (((2*k) + 384) ^ swz)) = f2bf((ac*cv + as*sv) * XAVIER);
            }
        }

        // bias partials: waves 4..7 (k-parallel over 128 threads per output)
        if (tid >= 256) {
            const int t2 = tid - 256;
            const int g  = t2 >> 7;
            const int k0 = t2 & 127;
            const int j  = 2*b + g;
            const float jj = (j + 1.0f) * (1.0f / (OUT_DIM + 1.0f));
            float bp = 0.0f;
            {
                float s, c;
                fsincos(fmaf(jj, omega[3*k0+1], fmaf(l, omega[3*k0+2], phi[k0])), s, c);
                bp = fmaf(alpha_bias[k0], s, fmaf(alpha_bias[NK + k0], c, bp));
            }
            if (k0 < 64) {
                const int k = k0 + 128;
                float s, c;
                fsincos(fmaf(jj, omega[3*k+1], fmaf(l, omega[3*k+2], phi[k])), s, c);
                bp = fmaf(alpha_bias[k], s, fmaf(alpha_bias[NK + k], c, bp));
            }
            #pragma unroll
            for (int off = 32; off > 0; off >>= 1)
                bp += __shfl_down(bp, off);
            if ((tid & 63) == 0) bsc[t2 >> 6] = bp;
        }
        __syncthreads();

        // 32x32x384 tile GEMM (waves 0..3) -> Wt; bias finalize (2 threads)
        if (tid < 256) {
            const int wave = tid >> 6, lane = tid & 63;
            const int wr = wave >> 1, wc = wave & 1;
            f32x4 acc = {};
            #pragma unroll
            for (int kk = 0; kk < KF / 32; ++kk) {
                const int kb = kk * 64 + (lane >> 4) * 16;
                const int ra = wr*16 + (lane & 15);
                const int rb = wc*16 + (lane & 15);
                bf16x8 a = *reinterpret_cast<const bf16x8*>(
                    sV + ra*768 + (kb ^ ((ra & 7) << 4)));
                bf16x8 bb = *reinterpret_cast<const bf16x8*>(
                    sU + rb*768 + (kb ^ ((rb & 7) << 4)));
                acc = __builtin_amdgcn_mfma_f32_16x16x32_bf16(a, bb, acc, 0, 0, 0);
            }
            const int row = j0 + wr*16 + (lane >> 4) * 4;   // out col j
            const int col = i0 + wc*16 + (lane & 15);       // in row i
            #pragma unroll
            for (int r = 0; r < 4; ++r)
                Wt[(size_t)(row + r) * IN_DIM + col] = f2bf(acc[r]);
        }
        if (tid == 256) bias[2*b    ] = (bsc[0] + bsc[1]) * BIAS_SCALE;
        if (tid == 257) bias[2*b + 1] = (bsc[2] + bsc[3]) * BIAS_SCALE;
    }

    // ---- phase B addressing (needed for the x prefetch below) -----------
    const int w    = tid >> 6, lane = tid & 63;
    const int brow = b * 32;
    const int bsrc  = ((lane & 7) * 16) ^ ((lane >> 3) << 4);
    const int bjrow = lane >> 3;
    const int arow = tid >> 4;
    const int akq  = tid & 15;
    const int adst = arow * 128 + (((akq * 8)) ^ ((arow & 7) << 4));
    const size_t xoff = (size_t)(brow + arow) * IN_DIM + akq * 4;

    // prefetch x for steps 0,1 (independent of Wt) -> hides HBM under barrier
    f32x4 av0 = *reinterpret_cast<const f32x4*>(&X[xoff]);
    f32x4 av1 = *reinterpret_cast<const f32x4*>(&X[xoff + 64]);

    // ======================= grid barrier ================================
    // __syncthreads drains every wave's vmcnt(0): all Wt/bias stores are in
    // L2 before the release; agent-scope rel/acq does cross-XCD wb/inv.
    __syncthreads();
    if (tid == 0) {
        __hip_atomic_fetch_add(ctr, 1u, __ATOMIC_ACQ_REL, __HIP_MEMORY_SCOPE_AGENT);
        while (__hip_atomic_load(ctr, __ATOMIC_ACQUIRE, __HIP_MEMORY_SCOPE_AGENT)
               < (u32)gridDim.x)
            __builtin_amdgcn_s_sleep(2);
    }
    __syncthreads();

    // ======================= Phase B: main GEMM ==========================
    f32x4 acc[2][4] = {};

    auto stageB = [&](int buf, int k0) {
        #pragma unroll
        for (int c = 0; c < 8; ++c) {
            const int ci = w * 8 + c;
            const int j  = ci * 8 + bjrow;
            gload_lds16((const char*)Wt + (size_t)j * (IN_DIM * 2) + k0 * 2 + bsrc,
                        sB + buf * 65536 + ci * 1024);
        }
    };
    auto loadA = [&](int k0) -> f32x4 {
        return *reinterpret_cast<const f32x4*>(&X[xoff + k0]);
    };
    auto writeA = [&](int buf, f32x4 v) {
        u64 p = (u64)pack2bf(v.x, v.y) | ((u64)pack2bf(v.z, v.w) << 32);
        *reinterpret_cast<u64*>(sA + buf * 4096 + adst) = p;
    };
    auto compute = [&](int buf) {
        #pragma unroll
        for (int kk = 0; kk < 2; ++kk) {
            const int kb = kk * 64 + (lane >> 4) * 16;
            bf16x8 a[2], bb[4];
            #pragma unroll
            for (int m = 0; m < 2; ++m) {
                const int r = m*16 + (lane & 15);
                a[m] = *reinterpret_cast<const bf16x8*>(
                    sA + buf * 4096 + r*128 + (kb ^ ((r & 7) << 4)));
            }
            #pragma unroll
            for (int n = 0; n < 4; ++n) {
                const int j = w*64 + n*16 + (lane & 15);
                bb[n] = *reinterpret_cast<const bf16x8*>(
                    sB + buf * 65536 + j*128 + (kb ^ ((j & 7) << 4)));
            }
            #pragma unroll
            for (int m = 0; m < 2; ++m)
                #pragma unroll
                for (int n = 0; n < 4; ++n)
                    acc[m][n] = __builtin_amdgcn_mfma_f32_16x16x32_bf16(
                        a[m], bb[n], acc[m][n], 0, 0, 0);
        }
    };

    #define VMW(n)  asm volatile("s_waitcnt vmcnt(" #n ")" ::: "memory")
    #define LGKM0   asm volatile("s_waitcnt lgkmcnt(0)" ::: "memory")
    #define BARRIER do { __builtin_amdgcn_s_barrier(); \
                         asm volatile("" ::: "memory"); } while (0)

    // prologue: stage steps 0 and 1 (A-values already in av0/av1)
    stageB(0, 0);
    stageB(1, 64);
    writeA(0, av0);       // compiler inserts the wait for av0/av1
    writeA(1, av1);
    VMW(8);               // retires B(0) fully; B(1) stays in flight
    LGKM0;                // my ds_writes committed
    BARRIER;              // B(0)+A(0)+A(1) published

    #pragma unroll
    for (int t = 0; t < 8; ++t) {
        compute(t & 1);       // B(t),A(t) guaranteed by barrier at end of t-1
        BARRIER;              // buf[t&1] free to overwrite
        if (t < 6) {
            f32x4 av = loadA((t + 2) * 64);
            stageB(t & 1, (t + 2) * 64);
            VMW(8);           // retires B(t+1) + av(t+2); 8 B(t+2) stay in flight
            writeA(t & 1, av);
        } else if (t == 6) {
            VMW(0);           // drain B(7)
        }
        LGKM0;
        BARRIER;              // publish B(t+1) (+ A(t+2))
    }

    #undef VMW
    #undef LGKM0
    #undef BARRIER

    // epilogue
    #pragma unroll
    for (int n = 0; n < 4; ++n) {
        const int col = w*64 + n*16 + (lane & 15);
        const float bv = bias[col];
        #pragma unroll
        for (int m = 0; m < 2; ++m) {
            const int row0 = brow + m*16 + (lane >> 4) * 4;
            #pragma unroll
            for (int r = 0; r < 4; ++r)
                out[(size_t)(row0 + r) * OUT_DIM + col] = acc[m][n][r] + bv;
        }
    }
}

// ---------------------------------------------------------------------------
extern "C" void kernel_launch(void* const* d_in, const int* in_sizes, int n_in,
                              void* d_out, int out_size, void* d_ws, size_t ws_size,
                              hipStream_t stream) {
    const float* x          = (const float*)d_in[0];
    const float* omega      = (const float*)d_in[1];
    const float* phi        = (const float*)d_in[2];
    const float* alpha      = (const float*)d_in[3];
    const float* alpha_bias = (const float*)d_in[4];
    const int*   layer_idx  = (const int*)d_in[5];
    const int*   num_layers = (const int*)d_in[6];
    float* out = (float*)d_out;

    const int M = in_sizes[0] / IN_DIM;   // 8192

    u16*   Wt   = (u16*)d_ws;                                  // 512KB
    float* bias = (float*)((char*)d_ws + 512 * 1024);          // 2KB
    u32*   ctr  = (u32*)((char*)d_ws + 516 * 1024);            // 4B ticket

    hipMemsetAsync(ctr, 0, 4, stream);                         // reset barrier
    fourier_fused<<<M / 32, 512, 0, stream>>>(
        x, omega, phi, alpha, alpha_bias, layer_idx, num_layers,
        Wt, bias, ctr, out, M);
}

// Round 3
// 24.297 us; speedup vs baseline: 1.7029x; 1.7029x over previous
//
#include <hip/hip_runtime.h>
#include <hip/hip_bf16.h>
#include <math.h>

#define IN_DIM   512
#define OUT_DIM  512
#define NK       192          // TOTAL_K
#define KF       384          // 2*TOTAL_K
#define XAVIER   0.04419417382415922f
#define BIAS_SCALE 0.02f

typedef __attribute__((ext_vector_type(8))) short bf16x8;
typedef __attribute__((ext_vector_type(4))) float f32x4;
typedef unsigned short u16;
typedef unsigned int   u32;
typedef unsigned long long u64;

__device__ inline u16 f2bf(float f) {
    __hip_bfloat16 h = __float2bfloat16(f);
    return *reinterpret_cast<u16*>(&h);
}
__device__ inline u32 pack2bf(float lo, float hi) {
    return (u32)f2bf(lo) | ((u32)f2bf(hi) << 16);
}
__device__ inline void gload_lds16(const void* g, void* l) {
    __builtin_amdgcn_global_load_lds(
        (const __attribute__((address_space(1))) void*)g,
        (__attribute__((address_space(3))) void*)l, 16, 0, 0);
}
// Native-rate sincos (revolutions). |arg| < ~50 rad here; err ~1e-6 << bf16 W quant.
__device__ inline void fsincos(float x, float& s, float& c) {
    float t = x * 0.15915494309189535f;   // 1/(2*pi)
    t -= floorf(t);
    s = __builtin_amdgcn_sinf(t);
    c = __builtin_amdgcn_cosf(t);
}

// ---------------------------------------------------------------------------
// Kernel 1: 256 blocks x 512 threads (unchanged from the 24.1us round).
// ---------------------------------------------------------------------------
__global__ __launch_bounds__(512) void synth_fused(
    const float* __restrict__ omega, const float* __restrict__ phi,
    const float* __restrict__ alpha, const float* __restrict__ alpha_bias,
    const int* __restrict__ layer_idx, const int* __restrict__ num_layers,
    u16* __restrict__ Wt, float* __restrict__ bias)
{
    const int b   = blockIdx.x;
    const int tid = threadIdx.x;
    const float l = ((float)layer_idx[0] + 1.0f) / ((float)num_layers[0] + 1.0f);

    __shared__ u16 sV[32 * KF];   // 24KB
    __shared__ u16 sU[32 * KF];   // 24KB
    __shared__ float bsc[4];

    const int bi = b & 15, bj = b >> 4;
    const int i0 = bi * 32, j0 = bj * 32;

    #pragma unroll 4
    for (int q = 0; q < 12; ++q) {
        const int e  = q * 512 + tid;     // 0..6143
        const int rl = e / NK;
        const int k  = e - rl * NK;
        const int swz  = (rl & 7) << 4;
        const int base = rl * (KF * 2);
        const float om0 = omega[3*k], om1 = omega[3*k+1], om2 = omega[3*k+2];
        const float ph  = phi[k];
        {
            const float ii = (i0 + rl + 1.0f) * (1.0f / (IN_DIM + 1.0f));
            float s, c; fsincos(fmaf(ii, om0, fmaf(l, om2, ph)), s, c);
            *(u16*)((char*)sU + base + (((2*k)      ) ^ swz)) = f2bf(s);
            *(u16*)((char*)sU + base + (((2*k) + 384) ^ swz)) = f2bf(c);
        }
        {
            const float jj = (j0 + rl + 1.0f) * (1.0f / (OUT_DIM + 1.0f));
            float sv, cv; fsincos(jj * om1, sv, cv);
            const float as = alpha[k], ac = alpha[NK + k];
            *(u16*)((char*)sV + base + (((2*k)      ) ^ swz)) = f2bf((as*cv - ac*sv) * XAVIER);
            *(u16*)((char*)sV + base + (((2*k) + 384) ^ swz)) = f2bf((ac*cv + as*sv) * XAVIER);
        }
    }

    // bias partials: waves 4..7 (k-parallel, 128 threads per output)
    if (tid >= 256) {
        const int t2 = tid - 256;
        const int g  = t2 >> 7;
        const int k0 = t2 & 127;
        const int j  = 2*b + g;
        const float jj = (j + 1.0f) * (1.0f / (OUT_DIM + 1.0f));
        float bp = 0.0f;
        {
            float s, c;
            fsincos(fmaf(jj, omega[3*k0+1], fmaf(l, omega[3*k0+2], phi[k0])), s, c);
            bp = fmaf(alpha_bias[k0], s, fmaf(alpha_bias[NK + k0], c, bp));
        }
        if (k0 < 64) {
            const int k = k0 + 128;
            float s, c;
            fsincos(fmaf(jj, omega[3*k+1], fmaf(l, omega[3*k+2], phi[k])), s, c);
            bp = fmaf(alpha_bias[k], s, fmaf(alpha_bias[NK + k], c, bp));
        }
        #pragma unroll
        for (int off = 32; off > 0; off >>= 1)
            bp += __shfl_down(bp, off);
        if ((tid & 63) == 0) bsc[t2 >> 6] = bp;
    }
    __syncthreads();

    // 32x32x384 tile GEMM (waves 0..3) -> Wt
    if (tid < 256) {
        const int wave = tid >> 6, lane = tid & 63;
        const int wr = wave >> 1, wc = wave & 1;
        f32x4 acc = {};
        #pragma unroll
        for (int kk = 0; kk < KF / 32; ++kk) {
            const int kb = kk * 64 + (lane >> 4) * 16;
            const int ra = wr*16 + (lane & 15);
            const int rb = wc*16 + (lane & 15);
            bf16x8 a = *reinterpret_cast<const bf16x8*>(
                (const char*)sV + ra*768 + (kb ^ ((ra & 7) << 4)));
            bf16x8 bb = *reinterpret_cast<const bf16x8*>(
                (const char*)sU + rb*768 + (kb ^ ((rb & 7) << 4)));
            acc = __builtin_amdgcn_mfma_f32_16x16x32_bf16(a, bb, acc, 0, 0, 0);
        }
        const int row = j0 + wr*16 + (lane >> 4) * 4;   // out col j
        const int col = i0 + wc*16 + (lane & 15);       // in row i
        #pragma unroll
        for (int r = 0; r < 4; ++r)
            Wt[(size_t)(row + r) * IN_DIM + col] = f2bf(acc[r]);
    }
    if (tid == 256) bias[2*b    ] = (bsc[0] + bsc[1]) * BIAS_SCALE;
    if (tid == 257) bias[2*b + 1] = (bsc[2] + bsc[3]) * BIAS_SCALE;
}

// ---------------------------------------------------------------------------
// Kernel 2: out = x @ W + b.  Round-1 pipeline + PER-BLOCK K-PHASE STAGGER:
// without it, all 256 blocks sweep the same 512KB Wt in the same order in
// lockstep -> all 32 CUs of an XCD demand the same L2 lines at the same
// instant -> one L2 bank serializes 32 reads while others idle. Staggering
// the (commutative) K-sum start by ph=(b>>3)&7 (co-XCD blocks differ in b>>3)
// spreads co-resident blocks across 8 disjoint 64KB regions: 4-way instead
// of 32-way same-line contention.
// ---------------------------------------------------------------------------
__global__ __launch_bounds__(512) void main_gemm(
    const float* __restrict__ X, const u16* __restrict__ Wt,
    const float* __restrict__ bias, float* __restrict__ out, int M)
{
    __shared__ u16 sA[2][32 * 64];    // 2 x 4KB
    __shared__ u16 sB[2][512 * 64];   // 2 x 64KB

    const int tid  = threadIdx.x;
    const int w    = tid >> 6, lane = tid & 63;
    const int brow = blockIdx.x * 32;
    const int ph   = (blockIdx.x >> 3) & 7;   // K-phase stagger

    f32x4 acc[2][4] = {};

    const int bsrc  = ((lane & 7) * 16) ^ ((lane >> 3) << 4);
    const int bjrow = lane >> 3;
    const int arow = tid >> 4;
    const int akq  = tid & 15;
    const int adst = arow * 128 + (((akq * 8)) ^ ((arow & 7) << 4));
    const size_t xoff = (size_t)(brow + arow) * IN_DIM + akq * 4;

    auto kof = [&](int s) -> int { return ((s + ph) & 7) * 64; };

    auto stageB = [&](int buf, int k0) {
        #pragma unroll
        for (int c = 0; c < 8; ++c) {
            const int ci = w * 8 + c;
            const int j  = ci * 8 + bjrow;
            gload_lds16((const char*)Wt + (size_t)j * (IN_DIM * 2) + k0 * 2 + bsrc,
                        (char*)&sB[buf][0] + ci * 1024);
        }
    };
    auto loadA = [&](int k0) -> f32x4 {
        return *reinterpret_cast<const f32x4*>(&X[xoff + k0]);
    };
    auto writeA = [&](int buf, f32x4 v) {
        u64 p = (u64)pack2bf(v.x, v.y) | ((u64)pack2bf(v.z, v.w) << 32);
        *reinterpret_cast<u64*>((char*)&sA[buf][0] + adst) = p;
    };
    auto compute = [&](int buf) {
        #pragma unroll
        for (int kk = 0; kk < 2; ++kk) {
            const int kb = kk * 64 + (lane >> 4) * 16;
            bf16x8 a[2], bb[4];
            #pragma unroll
            for (int m = 0; m < 2; ++m) {
                const int r = m*16 + (lane & 15);
                a[m] = *reinterpret_cast<const bf16x8*>(
                    (const char*)&sA[buf][0] + r*128 + (kb ^ ((r & 7) << 4)));
            }
            #pragma unroll
            for (int n = 0; n < 4; ++n) {
                const int j = w*64 + n*16 + (lane & 15);
                bb[n] = *reinterpret_cast<const bf16x8*>(
                    (const char*)&sB[buf][0] + j*128 + (kb ^ ((j & 7) << 4)));
            }
            #pragma unroll
            for (int m = 0; m < 2; ++m)
                #pragma unroll
                for (int n = 0; n < 4; ++n)
                    acc[m][n] = __builtin_amdgcn_mfma_f32_16x16x32_bf16(
                        a[m], bb[n], acc[m][n], 0, 0, 0);
        }
    };

    #define VMW(n)  asm volatile("s_waitcnt vmcnt(" #n ")" ::: "memory")
    #define LGKM0   asm volatile("s_waitcnt lgkmcnt(0)" ::: "memory")
    #define BARRIER do { __builtin_amdgcn_s_barrier(); \
                         asm volatile("" ::: "memory"); } while (0)

    // prologue: stage steps 0 and 1 (staggered k order)
    {
        f32x4 av = loadA(kof(0));
        stageB(0, kof(0));
        VMW(8);               // av(0) ready (8 B(0) still in flight)
        writeA(0, av);
        av = loadA(kof(1));
        stageB(1, kof(1));
        VMW(8);               // retires B(0) fully + av(1); B(1) in flight
        writeA(1, av);
        LGKM0;
        BARRIER;              // B(0)+A(0)+A(1) published
    }

    #pragma unroll
    for (int t = 0; t < 8; ++t) {
        compute(t & 1);       // step t (k = kof(t)) guaranteed by prior barrier
        BARRIER;              // buf[t&1] free to overwrite
        if (t < 6) {
            f32x4 av = loadA(kof(t + 2));
            stageB(t & 1, kof(t + 2));
            VMW(8);           // retires B(t+1) + av(t+2); 8 B(t+2) stay in flight
            writeA(t & 1, av);
        } else if (t == 6) {
            VMW(0);           // drain B(7)
        }
        LGKM0;
        BARRIER;              // publish B(t+1) (+ A(t+2))
    }

    #undef VMW
    #undef LGKM0
    #undef BARRIER

    // epilogue
    #pragma unroll
    for (int n = 0; n < 4; ++n) {
        const int col = w*64 + n*16 + (lane & 15);
        const float bv = bias[col];
        #pragma unroll
        for (int m = 0; m < 2; ++m) {
            const int row0 = brow + m*16 + (lane >> 4) * 4;
            #pragma unroll
            for (int r = 0; r < 4; ++r)
                out[(size_t)(row0 + r) * OUT_DIM + col] = acc[m][n][r] + bv;
        }
    }
}

// ---------------------------------------------------------------------------
extern "C" void kernel_launch(void* const* d_in, const int* in_sizes, int n_in,
                              void* d_out, int out_size, void* d_ws, size_t ws_size,
                              hipStream_t stream) {
    const float* x          = (const float*)d_in[0];
    const float* omega      = (const float*)d_in[1];
    const float* phi        = (const float*)d_in[2];
    const float* alpha      = (const float*)d_in[3];
    const float* alpha_bias = (const float*)d_in[4];
    const int*   layer_idx  = (const int*)d_in[5];
    const int*   num_layers = (const int*)d_in[6];
    float* out = (float*)d_out;

    const int M = in_sizes[0] / IN_DIM;   // 8192

    u16*   Wt   = (u16*)d_ws;                                  // 512KB
    float* bias = (float*)((char*)d_ws + 512 * 1024);          // 2KB

    synth_fused<<<256, 512, 0, stream>>>(omega, phi, alpha, alpha_bias,
                                         layer_idx, num_layers, Wt, bias);
    main_gemm<<<M / 32, 512, 0, stream>>>(x, Wt, bias, out, M);
}